// Round 15
// baseline (161.725 us; speedup 1.0000x reference)
//
#include <hip/hip_runtime.h>
#include <hip/hip_bf16.h>
#include <math.h>

#define BB 32
#define NN 512
#define LL 4096
#define GG 128
#define DD 64   // DIM
#define AS 36   // scores A-tile LDS row stride in u32 words
#define RS2 36  // V S-tile row stride in u32 words (32 + 4 pad)

typedef __attribute__((ext_vector_type(4))) float f32x4;
typedef __attribute__((ext_vector_type(8))) short bf16x8;
typedef __attribute__((ext_vector_type(4))) unsigned u32x4;
typedef __attribute__((ext_vector_type(4))) unsigned short u16x4;

__device__ inline float sx(float v, int m) { return __shfl_xor(v, m, 64); }

// ------- K1 (merged nodes+adjT): adjT16[s][l] = tanh(3*(n1[l]·n2[s]-n2[l]·n1[s]))
// Each block (l0 = bx*64, s0 = by*16) recomputes its 80 node-rows (64 l + 16 s)
// into LDS (phase A, ~2560 FMA/thread, emb loads wave-uniform -> scalar path,
// w1/w2 L1-resident), then does the antisymmetric dots from LDS (phase B,
// stride-65 rows -> 2-way conflict = free). Kills the nodes kernel + its gap
// + all n1/n2/n1T/n2T global traffic.
__global__ __launch_bounds__(256) void ga_graph(
    const int* __restrict__ idx,
    const float* __restrict__ emb1, const float* __restrict__ emb2,
    const float* __restrict__ w1, const float* __restrict__ b1,
    const float* __restrict__ w2, const float* __restrict__ b2,
    __hip_bfloat16* __restrict__ adjT16) {
  int l0 = blockIdx.x * 64, s0 = blockIdx.y * 16;
  int tid = threadIdx.x;
  int d = tid & 63;      // output column
  int rw = tid >> 6;     // wave id = row offset

  __shared__ float n1L[64][65], n2L[64][65];  // l-rows (lane-indexed reads)
  __shared__ float n1S[16][64], n2S[16][64];  // s-rows (wave-uniform reads)

  // phase A: 80 rows, 4 at a time (one per wave; row uniform within wave)
  #pragma unroll 1
  for (int rr = 0; rr < 80; rr += 4) {
    int r = rr + rw;
    int gi = (r < 64) ? (l0 + r) : (s0 + r - 64);
    int ii = idx[gi];
    const float* e1 = emb1 + (size_t)ii * DD;
    const float* e2 = emb2 + (size_t)ii * DD;
    float a1 = 0.f, a2 = 0.f;
    #pragma unroll 8
    for (int k = 0; k < DD; ++k) {
      a1 += e1[k] * w1[k * DD + d];
      a2 += e2[k] * w2[k * DD + d];
    }
    float v1 = tanhf(3.f * (a1 + b1[d]));
    float v2 = tanhf(3.f * (a2 + b2[d]));
    if (r < 64) {
      n1L[r][d] = v1; n2L[r][d] = v2;
    } else {
      n1S[r - 64][d] = v1; n2S[r - 64][d] = v2;
    }
  }
  __syncthreads();

  // phase B: lane ll owns l = l0+ll; wave rw owns s-rows rw*4..rw*4+3
  int ll = d;
  float d1[4] = {0.f, 0.f, 0.f, 0.f}, d2[4] = {0.f, 0.f, 0.f, 0.f};
  #pragma unroll
  for (int kb = 0; kb < 4; ++kb) {
    float a1[16], a2[16];
    #pragma unroll
    for (int k = 0; k < 16; ++k) {
      a1[k] = n1L[ll][kb * 16 + k];
      a2[k] = n2L[ll][kb * 16 + k];
    }
    #pragma unroll
    for (int si = 0; si < 4; ++si) {
      int sr = rw * 4 + si;
      #pragma unroll
      for (int k = 0; k < 16; ++k) {
        d1[si] += a1[k] * n2S[sr][kb * 16 + k];
        d2[si] += a2[k] * n1S[sr][kb * 16 + k];
      }
    }
  }
  #pragma unroll
  for (int si = 0; si < 4; ++si) {
    int s = s0 + rw * 4 + si;
    adjT16[(size_t)s * NN + l0 + ll] =
        __float2bfloat16(tanhf(3.f * (d1[si] - d2[si])));
  }
}

// ---------------- K2 (mlp v4): t[b][n] only (64 KB total; RT round-trip gone)
// Coalesced w-loads (32B lane stride), 4 x-rows/block, 32-val reduction.
__global__ __launch_bounds__(256) void ga_mlp(
    const float* __restrict__ x, const float* __restrict__ mlp_w,
    const float* __restrict__ mlp_b, float* __restrict__ t_out) {
  int b = blockIdx.y;
  int j0 = blockIdx.x * 4;   // x-row base, 0..60
  int n0 = j0 * 8;           // t base
  int tid = threadIdx.x;
  const float* xb = x + (size_t)b * NN * LL;

  float acc[4][8];
  #pragma unroll
  for (int r = 0; r < 4; ++r)
    #pragma unroll
    for (int c = 0; c < 8; ++c) acc[r][c] = 0.f;

  #pragma unroll 4
  for (int it = 0; it < 16; ++it) {
    int l = it * 256 + tid;
    float4 w0 = *(const float4*)(mlp_w + (size_t)l * 8);
    float4 w1 = *(const float4*)(mlp_w + (size_t)l * 8 + 4);
    float wv[8] = {w0.x, w0.y, w0.z, w0.w, w1.x, w1.y, w1.z, w1.w};
    float xv[4];
    #pragma unroll
    for (int r = 0; r < 4; ++r) xv[r] = xb[(size_t)(j0 + r) * LL + l];
    #pragma unroll
    for (int r = 0; r < 4; ++r)
      #pragma unroll
      for (int c = 0; c < 8; ++c) acc[r][c] += xv[r] * wv[c];
  }
  #pragma unroll
  for (int r = 0; r < 4; ++r)
    #pragma unroll
    for (int c = 0; c < 8; ++c) {
      float v = acc[r][c];
      for (int off = 32; off; off >>= 1) v += __shfl_down(v, off);
      acc[r][c] = v;
    }
  __shared__ float red[4][32];
  int lane = tid & 63, wave = tid >> 6;
  if (lane == 0) {
    #pragma unroll
    for (int r = 0; r < 4; ++r)
      #pragma unroll
      for (int c = 0; c < 8; ++c) red[wave][r * 8 + c] = acc[r][c];
  }
  __syncthreads();
  if (tid < 32) {
    float s = red[0][tid] + red[1][tid] + red[2][tid] + red[3][tid];
    t_out[(size_t)b * NN + n0 + tid] = tanhf(s + mlp_b[tid & 7]);
  }
}

// ------- K3 (scores v2, MFMA): B-fragments built on the fly from t + wsel ---
// scores[b,s,g] = sum_l adjT[s,l]*relu(t[b,l]*w_g); softmax over g;
// seriesT[b][g][s] bf16. No RT buffer, no B staging: bfr = bf16(relu(tv*wg)).
__global__ __launch_bounds__(256) void ga_scores_mfma(
    const __hip_bfloat16* __restrict__ adjT16,
    const float* __restrict__ t, const float* __restrict__ wsel,
    __hip_bfloat16* __restrict__ seriesT) {
  int b = blockIdx.y;
  int s0 = blockIdx.x * 64;
  int tid = threadIdx.x;
  __shared__ unsigned As[64 * AS];
  __shared__ float tl[NN];
  int wave = tid >> 6, lane = tid & 63, q = lane >> 4, mrow = lane & 15;
  const unsigned short* ap = (const unsigned short*)adjT16;

  tl[tid] = t[(size_t)b * NN + tid];
  tl[256 + tid] = t[(size_t)b * NN + 256 + tid];
  float wg[8];
  #pragma unroll
  for (int nf = 0; nf < 8; ++nf) wg[nf] = wsel[nf * 16 + mrow];

  f32x4 acc[8];
  #pragma unroll
  for (int nf = 0; nf < 8; ++nf) acc[nf] = (f32x4){0.f, 0.f, 0.f, 0.f};

  for (int l0 = 0; l0 < NN; l0 += 64) {
    #pragma unroll
    for (int it = 0; it < 2; ++it) {   // stage A: 64 rows x 8 parts
      int ci = it * 256 + tid;
      int row = ci >> 3, part = ci & 7;
      *(u32x4*)&As[row * AS + part * 4] =
          *(const u32x4*)(ap + (size_t)(s0 + row) * NN + l0 + part * 8);
    }
    __syncthreads();   // also covers tl on first iteration
    #pragma unroll
    for (int ks = 0; ks < 2; ++ks) {
      bf16x8 af = *(const bf16x8*)&As[(wave * 16 + mrow) * AS + ks * 16 + q * 4];
      float tv[8];
      int lb = l0 + ks * 32 + q * 8;
      #pragma unroll
      for (int j = 0; j < 8; ++j) tv[j] = tl[lb + j];
      #pragma unroll
      for (int nf = 0; nf < 8; ++nf) {
        unsigned w[4];
        #pragma unroll
        for (int p2 = 0; p2 < 4; ++p2) {
          __hip_bfloat162 pk = __float22bfloat162_rn(make_float2(
              fmaxf(tv[2 * p2] * wg[nf], 0.f),
              fmaxf(tv[2 * p2 + 1] * wg[nf], 0.f)));
          w[p2] = *(unsigned*)&pk;
        }
        bf16x8 bfr = *(bf16x8*)w;
        acc[nf] = __builtin_amdgcn_mfma_f32_16x16x32_bf16(af, bfr, acc[nf], 0, 0, 0);
      }
    }
    __syncthreads();
  }

  unsigned short* sT = (unsigned short*)seriesT + (size_t)b * GG * NN;
  f32x4 mx = acc[0];
  #pragma unroll
  for (int nf = 1; nf < 8; ++nf)
    #pragma unroll
    for (int r = 0; r < 4; ++r) mx[r] = fmaxf(mx[r], acc[nf][r]);
  #pragma unroll
  for (int m = 1; m <= 8; m <<= 1)
    #pragma unroll
    for (int r = 0; r < 4; ++r) mx[r] = fmaxf(mx[r], sx(mx[r], m));
  f32x4 sum = (f32x4){0.f, 0.f, 0.f, 0.f};
  #pragma unroll
  for (int nf = 0; nf < 8; ++nf)
    #pragma unroll
    for (int r = 0; r < 4; ++r) {
      float e = __expf(acc[nf][r] - mx[r]);
      acc[nf][r] = e;
      sum[r] += e;
    }
  #pragma unroll
  for (int m = 1; m <= 8; m <<= 1)
    #pragma unroll
    for (int r = 0; r < 4; ++r) sum[r] += sx(sum[r], m);
  f32x4 inv;
  #pragma unroll
  for (int r = 0; r < 4; ++r) inv[r] = 1.f / sum[r];
  int sbase = s0 + wave * 16 + q * 4;
  #pragma unroll
  for (int nf = 0; nf < 8; ++nf) {
    u16x4 pk;
    #pragma unroll
    for (int r = 0; r < 4; ++r)
      pk[r] = __bfloat16_as_ushort(__float2bfloat16(acc[nf][r] * inv[r]));
    *(u16x4*)(sT + (size_t)(nf * 16 + mrow) * NN + sbase) = pk;
  }
}

// ---------------- K4 (V, A/B-validated winner): ----------------
// out[b,p,g] = sum_l x[b,l,p] * seriesT[b,g,l]. X direct-to-register;
// S in LDS; K-step 64. ~At the cold-x HBM floor (~51us @ 6.3TB/s).
__global__ __launch_bounds__(256) void ga_V_mfma(
    const float* __restrict__ x, const __hip_bfloat16* __restrict__ seriesT,
    float* __restrict__ out) {
  int b = blockIdx.y;
  int p0 = blockIdx.x * 128;
  int tid = threadIdx.x;
  __shared__ unsigned St[128 * RS2];
  int wave = tid >> 6, lane = tid & 63, q = lane >> 4, mrow = lane & 15;
  int sgrow = tid >> 1;
  int sc0 = (tid & 1) * 4;
  const float* xb = x + (size_t)b * NN * LL;
  const unsigned short* sb = (const unsigned short*)seriesT + (size_t)b * GG * NN;
  int pcol = p0 + wave * 32 + mrow;

  f32x4 acc[2][8];
  #pragma unroll
  for (int mf = 0; mf < 2; ++mf)
    #pragma unroll
    for (int nf = 0; nf < 8; ++nf) acc[mf][nf] = (f32x4){0.f, 0.f, 0.f, 0.f};

  #pragma unroll 1
  for (int l0 = 0; l0 < NN; l0 += 64) {
    float xv[2][2][8];
    #pragma unroll
    for (int mf = 0; mf < 2; ++mf)
      #pragma unroll
      for (int ks = 0; ks < 2; ++ks) {
        const float* xp = xb + (size_t)(l0 + ks * 32 + q * 8) * LL + pcol + mf * 16;
        #pragma unroll
        for (int jj = 0; jj < 8; ++jj) xv[mf][ks][jj] = xp[(size_t)jj * LL];
      }
    u32x4 sv[4];
    #pragma unroll
    for (int k = 0; k < 4; ++k)
      sv[k] = *(const u32x4*)(sb + (size_t)sgrow * NN + l0 + (sc0 + k) * 8);
    #pragma unroll
    for (int k = 0; k < 4; ++k)
      *(u32x4*)&St[sgrow * RS2 + (sc0 + k) * 4] = sv[k];
    __syncthreads();

    bf16x8 af[2][2];
    #pragma unroll
    for (int mf = 0; mf < 2; ++mf)
      #pragma unroll
      for (int ks = 0; ks < 2; ++ks) {
        unsigned w[4];
        #pragma unroll
        for (int t = 0; t < 4; ++t) {
          __hip_bfloat162 pk = __float22bfloat162_rn(
              make_float2(xv[mf][ks][2 * t], xv[mf][ks][2 * t + 1]));
          w[t] = *(unsigned*)&pk;
        }
        af[mf][ks] = *(bf16x8*)w;
      }
    #pragma unroll
    for (int ks = 0; ks < 2; ++ks)
      #pragma unroll
      for (int nf = 0; nf < 8; ++nf) {
        bf16x8 bfr = *(const bf16x8*)&St[(nf * 16 + mrow) * RS2 + ks * 16 + q * 4];
        acc[0][nf] = __builtin_amdgcn_mfma_f32_16x16x32_bf16(af[0][ks], bfr, acc[0][nf], 0, 0, 0);
        acc[1][nf] = __builtin_amdgcn_mfma_f32_16x16x32_bf16(af[1][ks], bfr, acc[1][nf], 0, 0, 0);
      }
    __syncthreads();
  }

  #pragma unroll
  for (int mf = 0; mf < 2; ++mf) {
    int pb = p0 + wave * 32 + mf * 16 + q * 4;
    #pragma unroll
    for (int nf = 0; nf < 8; ++nf) {
      int g = nf * 16 + mrow;
      float* op = out + ((size_t)b * LL + pb) * GG + g;
      #pragma unroll
      for (int r = 0; r < 4; ++r) op[(size_t)r * GG] = acc[mf][nf][r];
    }
  }
}

extern "C" void kernel_launch(void* const* d_in, const int* in_sizes, int n_in,
                              void* d_out, int out_size, void* d_ws, size_t ws_size,
                              hipStream_t stream) {
  const int*   idx    = (const int*)d_in[0];
  const float* x      = (const float*)d_in[5];
  const float* emb1   = (const float*)d_in[6];
  const float* emb2   = (const float*)d_in[7];
  const float* lin1_w = (const float*)d_in[8];
  const float* lin1_b = (const float*)d_in[9];
  const float* lin2_w = (const float*)d_in[10];
  const float* lin2_b = (const float*)d_in[11];
  const float* mlp_w  = (const float*)d_in[12];
  const float* mlp_b  = (const float*)d_in[13];
  const float* W_sel  = (const float*)d_in[14];  // [8,128,1]; only h=0 row used
  float* out = (float*)d_out;

  float* ws = (float*)d_ws;
  float* t = ws;                                            // 32*512 fp32
  __hip_bfloat16* adjT16  = (__hip_bfloat16*)(ws + 16384);  // 512*512 bf16
  __hip_bfloat16* seriesT = (__hip_bfloat16*)(ws + 147456); // 32*128*512 bf16

  ga_graph<<<dim3(NN / 64, NN / 16), 256, 0, stream>>>(
      idx, emb1, emb2, lin1_w, lin1_b, lin2_w, lin2_b, adjT16);
  ga_mlp<<<dim3(16, BB), 256, 0, stream>>>(x, mlp_w, mlp_b, t);
  ga_scores_mfma<<<dim3(8, BB), 256, 0, stream>>>(adjT16, t, W_sel, seriesT);
  ga_V_mfma<<<dim3(LL / 128, BB), 256, 0, stream>>>(x, seriesT, out);
}

// Round 16
// 119.574 us; speedup vs baseline: 1.3525x; 1.3525x over previous
//
#include <hip/hip_runtime.h>
#include <hip/hip_bf16.h>
#include <math.h>

#define BB 32
#define NN 512
#define LL 4096
#define GG 128
#define DD 64   // DIM
#define AS 36   // scores A-tile LDS row stride in u32 words
#define RS2 36  // V S-tile row stride in u32 words (32 + 4 pad)

typedef __attribute__((ext_vector_type(4))) float f32x4;
typedef __attribute__((ext_vector_type(8))) short bf16x8;
typedef __attribute__((ext_vector_type(4))) unsigned u32x4;
typedef __attribute__((ext_vector_type(4))) unsigned short u16x4;

__device__ inline float sx(float v, int m) { return __shfl_xor(v, m, 64); }

// ---------------- K1: node embeddings n1, n2 [N, DIM] + transposes [DIM, N] --
// (R14-validated; R15's fused ga_graph was a 47us regression: 40x recompute
// redundancy at 1 wave/SIMD. Reverted.)
__global__ __launch_bounds__(64) void ga_nodes(
    const int* __restrict__ idx,
    const float* __restrict__ emb1, const float* __restrict__ emb2,
    const float* __restrict__ w1, const float* __restrict__ b1,
    const float* __restrict__ w2, const float* __restrict__ b2,
    float* __restrict__ n1, float* __restrict__ n2,
    float* __restrict__ n1T, float* __restrict__ n2T) {
  int i = blockIdx.x;
  int d = threadIdx.x;
  int ii = idx[i];
  const float* e1 = emb1 + ii * DD;
  const float* e2 = emb2 + ii * DD;
  float a1 = 0.f, a2 = 0.f;
  #pragma unroll 8
  for (int k = 0; k < DD; ++k) {
    a1 += e1[k] * w1[k * DD + d];
    a2 += e2[k] * w2[k * DD + d];
  }
  float v1 = tanhf(3.f * (a1 + b1[d]));
  float v2 = tanhf(3.f * (a2 + b2[d]));
  n1[i * DD + d] = v1;
  n2[i * DD + d] = v2;
  n1T[(size_t)d * NN + i] = v1;
  n2T[(size_t)d * NN + i] = v2;
}

// ------ K2 v3: adjT16[s][l] = tanh(3*(n1[l]·n2[s] - n2[l]·n1[s])), bf16 ------
// Coalesced k-major n1T/n2T reads (R9 fix; validated R10/R12).
__global__ __launch_bounds__(256) void ga_adjT(
    const float* __restrict__ n1, const float* __restrict__ n2,
    const float* __restrict__ n1T, const float* __restrict__ n2T,
    __hip_bfloat16* __restrict__ adjT16) {
  int l0 = blockIdx.x * 64, s0 = blockIdx.y * 16;
  int tid = threadIdx.x;
  int ll = tid & 63;
  int sw = __builtin_amdgcn_readfirstlane(tid >> 6);
  int l = l0 + ll;

  float d1[4] = {0.f, 0.f, 0.f, 0.f}, d2[4] = {0.f, 0.f, 0.f, 0.f};
  #pragma unroll
  for (int kb = 0; kb < 4; ++kb) {
    float a1[16], a2[16];
    #pragma unroll
    for (int k = 0; k < 16; ++k) {
      a1[k] = n1T[(size_t)(kb * 16 + k) * NN + l];
      a2[k] = n2T[(size_t)(kb * 16 + k) * NN + l];
    }
    #pragma unroll
    for (int si = 0; si < 4; ++si) {
      int s = s0 + sw * 4 + si;
      const float* s1 = n1 + (size_t)s * DD + kb * 16;
      const float* s2 = n2 + (size_t)s * DD + kb * 16;
      #pragma unroll
      for (int k = 0; k < 16; ++k) {
        d1[si] += a1[k] * s2[k];
        d2[si] += a2[k] * s1[k];
      }
    }
  }
  #pragma unroll
  for (int si = 0; si < 4; ++si) {
    int s = s0 + sw * 4 + si;
    adjT16[(size_t)s * NN + l] =
        __float2bfloat16(tanhf(3.f * (d1[si] - d2[si])));
  }
}

// ---------------- K3 (mlp v4): t[b][n] only (RT round-trip eliminated) -----
// Coalesced w-loads (32B lane stride), 4 x-rows/block, 32-val reduction.
__global__ __launch_bounds__(256) void ga_mlp(
    const float* __restrict__ x, const float* __restrict__ mlp_w,
    const float* __restrict__ mlp_b, float* __restrict__ t_out) {
  int b = blockIdx.y;
  int j0 = blockIdx.x * 4;   // x-row base, 0..60
  int n0 = j0 * 8;           // t base
  int tid = threadIdx.x;
  const float* xb = x + (size_t)b * NN * LL;

  float acc[4][8];
  #pragma unroll
  for (int r = 0; r < 4; ++r)
    #pragma unroll
    for (int c = 0; c < 8; ++c) acc[r][c] = 0.f;

  #pragma unroll 4
  for (int it = 0; it < 16; ++it) {
    int l = it * 256 + tid;
    float4 w0 = *(const float4*)(mlp_w + (size_t)l * 8);
    float4 w1 = *(const float4*)(mlp_w + (size_t)l * 8 + 4);
    float wv[8] = {w0.x, w0.y, w0.z, w0.w, w1.x, w1.y, w1.z, w1.w};
    float xv[4];
    #pragma unroll
    for (int r = 0; r < 4; ++r) xv[r] = xb[(size_t)(j0 + r) * LL + l];
    #pragma unroll
    for (int r = 0; r < 4; ++r)
      #pragma unroll
      for (int c = 0; c < 8; ++c) acc[r][c] += xv[r] * wv[c];
  }
  #pragma unroll
  for (int r = 0; r < 4; ++r)
    #pragma unroll
    for (int c = 0; c < 8; ++c) {
      float v = acc[r][c];
      for (int off = 32; off; off >>= 1) v += __shfl_down(v, off);
      acc[r][c] = v;
    }
  __shared__ float red[4][32];
  int lane = tid & 63, wave = tid >> 6;
  if (lane == 0) {
    #pragma unroll
    for (int r = 0; r < 4; ++r)
      #pragma unroll
      for (int c = 0; c < 8; ++c) red[wave][r * 8 + c] = acc[r][c];
  }
  __syncthreads();
  if (tid < 32) {
    float s = red[0][tid] + red[1][tid] + red[2][tid] + red[3][tid];
    t_out[(size_t)b * NN + n0 + tid] = tanhf(s + mlp_b[tid & 7]);
  }
}

// ------- K4 (scores v2, MFMA): B-fragments built on the fly from t + wsel ---
// scores[b,s,g] = sum_l adjT[s,l]*relu(t[b,l]*w_g); softmax over g;
// seriesT[b][g][s] bf16. No RT buffer, no B staging.
__global__ __launch_bounds__(256) void ga_scores_mfma(
    const __hip_bfloat16* __restrict__ adjT16,
    const float* __restrict__ t, const float* __restrict__ wsel,
    __hip_bfloat16* __restrict__ seriesT) {
  int b = blockIdx.y;
  int s0 = blockIdx.x * 64;
  int tid = threadIdx.x;
  __shared__ unsigned As[64 * AS];
  __shared__ float tl[NN];
  int wave = tid >> 6, lane = tid & 63, q = lane >> 4, mrow = lane & 15;
  const unsigned short* ap = (const unsigned short*)adjT16;

  tl[tid] = t[(size_t)b * NN + tid];
  tl[256 + tid] = t[(size_t)b * NN + 256 + tid];
  float wg[8];
  #pragma unroll
  for (int nf = 0; nf < 8; ++nf) wg[nf] = wsel[nf * 16 + mrow];

  f32x4 acc[8];
  #pragma unroll
  for (int nf = 0; nf < 8; ++nf) acc[nf] = (f32x4){0.f, 0.f, 0.f, 0.f};

  for (int l0 = 0; l0 < NN; l0 += 64) {
    #pragma unroll
    for (int it = 0; it < 2; ++it) {   // stage A: 64 rows x 8 parts
      int ci = it * 256 + tid;
      int row = ci >> 3, part = ci & 7;
      *(u32x4*)&As[row * AS + part * 4] =
          *(const u32x4*)(ap + (size_t)(s0 + row) * NN + l0 + part * 8);
    }
    __syncthreads();   // also covers tl on first iteration
    #pragma unroll
    for (int ks = 0; ks < 2; ++ks) {
      bf16x8 af = *(const bf16x8*)&As[(wave * 16 + mrow) * AS + ks * 16 + q * 4];
      float tv[8];
      int lb = l0 + ks * 32 + q * 8;
      #pragma unroll
      for (int j = 0; j < 8; ++j) tv[j] = tl[lb + j];
      #pragma unroll
      for (int nf = 0; nf < 8; ++nf) {
        unsigned w[4];
        #pragma unroll
        for (int p2 = 0; p2 < 4; ++p2) {
          __hip_bfloat162 pk = __float22bfloat162_rn(make_float2(
              fmaxf(tv[2 * p2] * wg[nf], 0.f),
              fmaxf(tv[2 * p2 + 1] * wg[nf], 0.f)));
          w[p2] = *(unsigned*)&pk;
        }
        bf16x8 bfr = *(bf16x8*)w;
        acc[nf] = __builtin_amdgcn_mfma_f32_16x16x32_bf16(af, bfr, acc[nf], 0, 0, 0);
      }
    }
    __syncthreads();
  }

  unsigned short* sT = (unsigned short*)seriesT + (size_t)b * GG * NN;
  f32x4 mx = acc[0];
  #pragma unroll
  for (int nf = 1; nf < 8; ++nf)
    #pragma unroll
    for (int r = 0; r < 4; ++r) mx[r] = fmaxf(mx[r], acc[nf][r]);
  #pragma unroll
  for (int m = 1; m <= 8; m <<= 1)
    #pragma unroll
    for (int r = 0; r < 4; ++r) mx[r] = fmaxf(mx[r], sx(mx[r], m));
  f32x4 sum = (f32x4){0.f, 0.f, 0.f, 0.f};
  #pragma unroll
  for (int nf = 0; nf < 8; ++nf)
    #pragma unroll
    for (int r = 0; r < 4; ++r) {
      float e = __expf(acc[nf][r] - mx[r]);
      acc[nf][r] = e;
      sum[r] += e;
    }
  #pragma unroll
  for (int m = 1; m <= 8; m <<= 1)
    #pragma unroll
    for (int r = 0; r < 4; ++r) sum[r] += sx(sum[r], m);
  f32x4 inv;
  #pragma unroll
  for (int r = 0; r < 4; ++r) inv[r] = 1.f / sum[r];
  int sbase = s0 + wave * 16 + q * 4;
  #pragma unroll
  for (int nf = 0; nf < 8; ++nf) {
    u16x4 pk;
    #pragma unroll
    for (int r = 0; r < 4; ++r)
      pk[r] = __bfloat16_as_ushort(__float2bfloat16(acc[nf][r] * inv[r]));
    *(u16x4*)(sT + (size_t)(nf * 16 + mrow) * NN + sbase) = pk;
  }
}

// ---------------- K5 (V, A/B-validated winner): ----------------
// out[b,p,g] = sum_l x[b,l,p] * seriesT[b,g,l]. X direct-to-register;
// S in LDS; K-step 64. ~At the cold-x HBM floor (~51us @ 6.3TB/s).
__global__ __launch_bounds__(256) void ga_V_mfma(
    const float* __restrict__ x, const __hip_bfloat16* __restrict__ seriesT,
    float* __restrict__ out) {
  int b = blockIdx.y;
  int p0 = blockIdx.x * 128;
  int tid = threadIdx.x;
  __shared__ unsigned St[128 * RS2];
  int wave = tid >> 6, lane = tid & 63, q = lane >> 4, mrow = lane & 15;
  int sgrow = tid >> 1;
  int sc0 = (tid & 1) * 4;
  const float* xb = x + (size_t)b * NN * LL;
  const unsigned short* sb = (const unsigned short*)seriesT + (size_t)b * GG * NN;
  int pcol = p0 + wave * 32 + mrow;

  f32x4 acc[2][8];
  #pragma unroll
  for (int mf = 0; mf < 2; ++mf)
    #pragma unroll
    for (int nf = 0; nf < 8; ++nf) acc[mf][nf] = (f32x4){0.f, 0.f, 0.f, 0.f};

  #pragma unroll 1
  for (int l0 = 0; l0 < NN; l0 += 64) {
    float xv[2][2][8];
    #pragma unroll
    for (int mf = 0; mf < 2; ++mf)
      #pragma unroll
      for (int ks = 0; ks < 2; ++ks) {
        const float* xp = xb + (size_t)(l0 + ks * 32 + q * 8) * LL + pcol + mf * 16;
        #pragma unroll
        for (int jj = 0; jj < 8; ++jj) xv[mf][ks][jj] = xp[(size_t)jj * LL];
      }
    u32x4 sv[4];
    #pragma unroll
    for (int k = 0; k < 4; ++k)
      sv[k] = *(const u32x4*)(sb + (size_t)sgrow * NN + l0 + (sc0 + k) * 8);
    #pragma unroll
    for (int k = 0; k < 4; ++k)
      *(u32x4*)&St[sgrow * RS2 + (sc0 + k) * 4] = sv[k];
    __syncthreads();

    bf16x8 af[2][2];
    #pragma unroll
    for (int mf = 0; mf < 2; ++mf)
      #pragma unroll
      for (int ks = 0; ks < 2; ++ks) {
        unsigned w[4];
        #pragma unroll
        for (int t = 0; t < 4; ++t) {
          __hip_bfloat162 pk = __float22bfloat162_rn(
              make_float2(xv[mf][ks][2 * t], xv[mf][ks][2 * t + 1]));
          w[t] = *(unsigned*)&pk;
        }
        af[mf][ks] = *(bf16x8*)w;
      }
    #pragma unroll
    for (int ks = 0; ks < 2; ++ks)
      #pragma unroll
      for (int nf = 0; nf < 8; ++nf) {
        bf16x8 bfr = *(const bf16x8*)&St[(nf * 16 + mrow) * RS2 + ks * 16 + q * 4];
        acc[0][nf] = __builtin_amdgcn_mfma_f32_16x16x32_bf16(af[0][ks], bfr, acc[0][nf], 0, 0, 0);
        acc[1][nf] = __builtin_amdgcn_mfma_f32_16x16x32_bf16(af[1][ks], bfr, acc[1][nf], 0, 0, 0);
      }
    __syncthreads();
  }

  #pragma unroll
  for (int mf = 0; mf < 2; ++mf) {
    int pb = p0 + wave * 32 + mf * 16 + q * 4;
    #pragma unroll
    for (int nf = 0; nf < 8; ++nf) {
      int g = nf * 16 + mrow;
      float* op = out + ((size_t)b * LL + pb) * GG + g;
      #pragma unroll
      for (int r = 0; r < 4; ++r) op[(size_t)r * GG] = acc[mf][nf][r];
    }
  }
}

extern "C" void kernel_launch(void* const* d_in, const int* in_sizes, int n_in,
                              void* d_out, int out_size, void* d_ws, size_t ws_size,
                              hipStream_t stream) {
  const int*   idx    = (const int*)d_in[0];
  const float* x      = (const float*)d_in[5];
  const float* emb1   = (const float*)d_in[6];
  const float* emb2   = (const float*)d_in[7];
  const float* lin1_w = (const float*)d_in[8];
  const float* lin1_b = (const float*)d_in[9];
  const float* lin2_w = (const float*)d_in[10];
  const float* lin2_b = (const float*)d_in[11];
  const float* mlp_w  = (const float*)d_in[12];
  const float* mlp_b  = (const float*)d_in[13];
  const float* W_sel  = (const float*)d_in[14];  // [8,128,1]; only h=0 row used
  float* out = (float*)d_out;

  float* ws = (float*)d_ws;
  float* n1  = ws;                                          // 32768 floats
  float* n2  = ws + 32768;
  float* n1T = ws + 65536;
  float* n2T = ws + 98304;
  float* t   = ws + 131072;                                 // 32*512 fp32
  __hip_bfloat16* adjT16  = (__hip_bfloat16*)(ws + 147456); // 512*512 bf16
  __hip_bfloat16* seriesT = (__hip_bfloat16*)(ws + 212992); // 32*128*512 bf16

  ga_nodes<<<NN, 64, 0, stream>>>(idx, emb1, emb2, lin1_w, lin1_b,
                                  lin2_w, lin2_b, n1, n2, n1T, n2T);
  ga_adjT<<<dim3(NN / 64, NN / 16), 256, 0, stream>>>(n1, n2, n1T, n2T, adjT16);
  ga_mlp<<<dim3(16, BB), 256, 0, stream>>>(x, mlp_w, mlp_b, t);
  ga_scores_mfma<<<dim3(8, BB), 256, 0, stream>>>(adjT16, t, W_sel, seriesT);
  ga_V_mfma<<<dim3(LL / 128, BB), 256, 0, stream>>>(x, seriesT, out);
}

// Round 18
// 114.595 us; speedup vs baseline: 1.4113x; 1.0435x over previous
//
#include <hip/hip_runtime.h>
#include <hip/hip_bf16.h>
#include <math.h>

#define BB 32
#define NN 512
#define LL 4096
#define GG 128
#define DD 64   // DIM
#define AS 36   // scores LDS row stride in u32 words
#define RS2 36  // V S-tile row stride in u32 words (32 + 4 pad)

typedef __attribute__((ext_vector_type(4))) float f32x4;
typedef __attribute__((ext_vector_type(8))) short bf16x8;
typedef __attribute__((ext_vector_type(4))) unsigned u32x4;
typedef __attribute__((ext_vector_type(4))) unsigned short u16x4;

__device__ inline float sx(float v, int m) { return __shfl_xor(v, m, 64); }

// ---------------- K1: node embeddings n1, n2 [N, DIM] + transposes [DIM, N] --
__global__ __launch_bounds__(64) void ga_nodes(
    const int* __restrict__ idx,
    const float* __restrict__ emb1, const float* __restrict__ emb2,
    const float* __restrict__ w1, const float* __restrict__ b1,
    const float* __restrict__ w2, const float* __restrict__ b2,
    float* __restrict__ n1, float* __restrict__ n2,
    float* __restrict__ n1T, float* __restrict__ n2T) {
  int i = blockIdx.x;
  int d = threadIdx.x;
  int ii = idx[i];
  const float* e1 = emb1 + ii * DD;
  const float* e2 = emb2 + ii * DD;
  float a1 = 0.f, a2 = 0.f;
  #pragma unroll 8
  for (int k = 0; k < DD; ++k) {
    a1 += e1[k] * w1[k * DD + d];
    a2 += e2[k] * w2[k * DD + d];
  }
  float v1 = tanhf(3.f * (a1 + b1[d]));
  float v2 = tanhf(3.f * (a2 + b2[d]));
  n1[i * DD + d] = v1;
  n2[i * DD + d] = v2;
  n1T[(size_t)d * NN + i] = v1;
  n2T[(size_t)d * NN + i] = v2;
}

// ------ K2 v3: adjT16[s][l] = tanh(3*(n1[l]·n2[s] - n2[l]·n1[s])), bf16 ------
// Coalesced k-major n1T/n2T reads (R9 fix; validated R10/R12).
__global__ __launch_bounds__(256) void ga_adjT(
    const float* __restrict__ n1, const float* __restrict__ n2,
    const float* __restrict__ n1T, const float* __restrict__ n2T,
    __hip_bfloat16* __restrict__ adjT16) {
  int l0 = blockIdx.x * 64, s0 = blockIdx.y * 16;
  int tid = threadIdx.x;
  int ll = tid & 63;
  int sw = __builtin_amdgcn_readfirstlane(tid >> 6);
  int l = l0 + ll;

  float d1[4] = {0.f, 0.f, 0.f, 0.f}, d2[4] = {0.f, 0.f, 0.f, 0.f};
  #pragma unroll
  for (int kb = 0; kb < 4; ++kb) {
    float a1[16], a2[16];
    #pragma unroll
    for (int k = 0; k < 16; ++k) {
      a1[k] = n1T[(size_t)(kb * 16 + k) * NN + l];
      a2[k] = n2T[(size_t)(kb * 16 + k) * NN + l];
    }
    #pragma unroll
    for (int si = 0; si < 4; ++si) {
      int s = s0 + sw * 4 + si;
      const float* s1 = n1 + (size_t)s * DD + kb * 16;
      const float* s2 = n2 + (size_t)s * DD + kb * 16;
      #pragma unroll
      for (int k = 0; k < 16; ++k) {
        d1[si] += a1[k] * s2[k];
        d2[si] += a2[k] * s1[k];
      }
    }
  }
  #pragma unroll
  for (int si = 0; si < 4; ++si) {
    int s = s0 + sw * 4 + si;
    adjT16[(size_t)s * NN + l] =
        __float2bfloat16(tanhf(3.f * (d1[si] - d2[si])));
  }
}

// ---------------- K3 v3: MLP + fused relu-select -> RT ----------------
// Coalesced w-loads (l = it*256+tid -> 32B lane stride), 4 rows/block,
// 32-value reduction. (R12 fix; validated R14: -9.9us vs v2.)
__global__ __launch_bounds__(256) void ga_mlp(
    const float* __restrict__ x, const float* __restrict__ mlp_w,
    const float* __restrict__ mlp_b, const float* __restrict__ wsel,
    __hip_bfloat16* __restrict__ RT) {
  int b = blockIdx.y;
  int j0 = blockIdx.x * 4;   // x-row base, 0..60
  int n0 = j0 * 8;           // t/l base
  int tid = threadIdx.x;
  const float* xb = x + (size_t)b * NN * LL;

  float acc[4][8];
  #pragma unroll
  for (int r = 0; r < 4; ++r)
    #pragma unroll
    for (int c = 0; c < 8; ++c) acc[r][c] = 0.f;

  #pragma unroll 4
  for (int it = 0; it < 16; ++it) {
    int l = it * 256 + tid;
    float4 w0 = *(const float4*)(mlp_w + (size_t)l * 8);
    float4 w1 = *(const float4*)(mlp_w + (size_t)l * 8 + 4);
    float wv[8] = {w0.x, w0.y, w0.z, w0.w, w1.x, w1.y, w1.z, w1.w};
    float xv[4];
    #pragma unroll
    for (int r = 0; r < 4; ++r) xv[r] = xb[(size_t)(j0 + r) * LL + l];
    #pragma unroll
    for (int r = 0; r < 4; ++r)
      #pragma unroll
      for (int c = 0; c < 8; ++c) acc[r][c] += xv[r] * wv[c];
  }
  #pragma unroll
  for (int r = 0; r < 4; ++r)
    #pragma unroll
    for (int c = 0; c < 8; ++c) {
      float v = acc[r][c];
      for (int off = 32; off; off >>= 1) v += __shfl_down(v, off);
      acc[r][c] = v;
    }
  __shared__ float red[4][32];
  __shared__ float tl[32];
  int lane = tid & 63, wave = tid >> 6;
  if (lane == 0) {
    #pragma unroll
    for (int r = 0; r < 4; ++r)
      #pragma unroll
      for (int c = 0; c < 8; ++c) red[wave][r * 8 + c] = acc[r][c];
  }
  __syncthreads();
  if (tid < 32) {
    float s = red[0][tid] + red[1][tid] + red[2][tid] + red[3][tid];
    tl[tid] = tanhf(s + mlp_b[tid & 7]);
  }
  __syncthreads();
  // RT write: 128 g x 32 l bf16 = 1024 u16x4 chunks, 4 per thread
  unsigned short* rp = (unsigned short*)RT + (size_t)b * GG * NN + n0;
  #pragma unroll
  for (int itw = 0; itw < 4; ++itw) {
    int f = itw * 256 + tid;
    int g = f >> 3, c4 = (f & 7) * 4;
    float w = wsel[g];
    u16x4 pk;
    #pragma unroll
    for (int k = 0; k < 4; ++k)
      pk[k] = __bfloat16_as_ushort(__float2bfloat16(fmaxf(tl[c4 + k] * w, 0.f)));
    *(u16x4*)(rp + (size_t)g * NN + c4) = pk;
  }
}

// ---------------- K4 (MFMA): scores GEMM + fused softmax -> seriesT bf16 ----
// RT-staged B (R16 showed on-the-fly B build is 4.8us slower).
__global__ __launch_bounds__(256) void ga_scores_mfma(
    const __hip_bfloat16* __restrict__ adjT16,
    const __hip_bfloat16* __restrict__ RT,
    __hip_bfloat16* __restrict__ seriesT) {
  int b = blockIdx.y;
  int s0 = blockIdx.x * 64;
  int tid = threadIdx.x;
  __shared__ unsigned As[64 * AS];
  __shared__ unsigned Bs[128 * AS];
  int wave = tid >> 6, lane = tid & 63, q = lane >> 4, mrow = lane & 15;
  const unsigned short* ap = (const unsigned short*)adjT16;
  const unsigned short* bp = (const unsigned short*)RT + (size_t)b * GG * NN;

  f32x4 acc[8];
  #pragma unroll
  for (int nf = 0; nf < 8; ++nf) acc[nf] = (f32x4){0.f, 0.f, 0.f, 0.f};

  for (int l0 = 0; l0 < NN; l0 += 64) {
    #pragma unroll
    for (int it = 0; it < 2; ++it) {
      int ci = it * 256 + tid;
      int row = ci >> 3, part = ci & 7;
      *(u32x4*)&As[row * AS + part * 4] =
          *(const u32x4*)(ap + (size_t)(s0 + row) * NN + l0 + part * 8);
    }
    #pragma unroll
    for (int it = 0; it < 4; ++it) {
      int ci = it * 256 + tid;
      int row = ci >> 3, part = ci & 7;
      *(u32x4*)&Bs[row * AS + part * 4] =
          *(const u32x4*)(bp + (size_t)row * NN + l0 + part * 8);
    }
    __syncthreads();
    #pragma unroll
    for (int ks = 0; ks < 2; ++ks) {
      bf16x8 af = *(const bf16x8*)&As[(wave * 16 + mrow) * AS + ks * 16 + q * 4];
      #pragma unroll
      for (int nf = 0; nf < 8; ++nf) {
        bf16x8 bfr = *(const bf16x8*)&Bs[(nf * 16 + mrow) * AS + ks * 16 + q * 4];
        acc[nf] = __builtin_amdgcn_mfma_f32_16x16x32_bf16(af, bfr, acc[nf], 0, 0, 0);
      }
    }
    __syncthreads();
  }

  unsigned short* sT = (unsigned short*)seriesT + (size_t)b * GG * NN;
  f32x4 mx = acc[0];
  #pragma unroll
  for (int nf = 1; nf < 8; ++nf)
    #pragma unroll
    for (int r = 0; r < 4; ++r) mx[r] = fmaxf(mx[r], acc[nf][r]);
  #pragma unroll
  for (int m = 1; m <= 8; m <<= 1)
    #pragma unroll
    for (int r = 0; r < 4; ++r) mx[r] = fmaxf(mx[r], sx(mx[r], m));
  f32x4 sum = (f32x4){0.f, 0.f, 0.f, 0.f};
  #pragma unroll
  for (int nf = 0; nf < 8; ++nf)
    #pragma unroll
    for (int r = 0; r < 4; ++r) {
      float e = __expf(acc[nf][r] - mx[r]);
      acc[nf][r] = e;
      sum[r] += e;
    }
  #pragma unroll
  for (int m = 1; m <= 8; m <<= 1)
    #pragma unroll
    for (int r = 0; r < 4; ++r) sum[r] += sx(sum[r], m);
  f32x4 inv;
  #pragma unroll
  for (int r = 0; r < 4; ++r) inv[r] = 1.f / sum[r];
  int sbase = s0 + wave * 16 + q * 4;
  #pragma unroll
  for (int nf = 0; nf < 8; ++nf) {
    u16x4 pk;
    #pragma unroll
    for (int r = 0; r < 4; ++r)
      pk[r] = __bfloat16_as_ushort(__float2bfloat16(acc[nf][r] * inv[r]));
    *(u16x4*)(sT + (size_t)(nf * 16 + mrow) * NN + sbase) = pk;
  }
}

// ---------------- K5 (V, A/B-validated winner): ----------------
// out[b,p,g] = sum_l x[b,l,p] * seriesT[b,g,l]. X direct-to-register
// (R13 A/B: ~26 vs 34.6 us/half for LDS-staged); S in LDS; K-step 64.
// ~90% of the cold-x HBM floor (256MB read + 67MB write ~ 51us @ 6.3TB/s).
__global__ __launch_bounds__(256) void ga_V_mfma(
    const float* __restrict__ x, const __hip_bfloat16* __restrict__ seriesT,
    float* __restrict__ out) {
  int b = blockIdx.y;
  int p0 = blockIdx.x * 128;
  int tid = threadIdx.x;
  __shared__ unsigned St[128 * RS2];
  int wave = tid >> 6, lane = tid & 63, q = lane >> 4, mrow = lane & 15;
  int sgrow = tid >> 1;
  int sc0 = (tid & 1) * 4;
  const float* xb = x + (size_t)b * NN * LL;
  const unsigned short* sb = (const unsigned short*)seriesT + (size_t)b * GG * NN;
  int pcol = p0 + wave * 32 + mrow;

  f32x4 acc[2][8];
  #pragma unroll
  for (int mf = 0; mf < 2; ++mf)
    #pragma unroll
    for (int nf = 0; nf < 8; ++nf) acc[mf][nf] = (f32x4){0.f, 0.f, 0.f, 0.f};

  #pragma unroll 1
  for (int l0 = 0; l0 < NN; l0 += 64) {
    float xv[2][2][8];
    #pragma unroll
    for (int mf = 0; mf < 2; ++mf)
      #pragma unroll
      for (int ks = 0; ks < 2; ++ks) {
        const float* xp = xb + (size_t)(l0 + ks * 32 + q * 8) * LL + pcol + mf * 16;
        #pragma unroll
        for (int jj = 0; jj < 8; ++jj) xv[mf][ks][jj] = xp[(size_t)jj * LL];
      }
    u32x4 sv[4];
    #pragma unroll
    for (int k = 0; k < 4; ++k)
      sv[k] = *(const u32x4*)(sb + (size_t)sgrow * NN + l0 + (sc0 + k) * 8);
    #pragma unroll
    for (int k = 0; k < 4; ++k)
      *(u32x4*)&St[sgrow * RS2 + (sc0 + k) * 4] = sv[k];
    __syncthreads();

    bf16x8 af[2][2];
    #pragma unroll
    for (int mf = 0; mf < 2; ++mf)
      #pragma unroll
      for (int ks = 0; ks < 2; ++ks) {
        unsigned w[4];
        #pragma unroll
        for (int t = 0; t < 4; ++t) {
          __hip_bfloat162 pk = __float22bfloat162_rn(
              make_float2(xv[mf][ks][2 * t], xv[mf][ks][2 * t + 1]));
          w[t] = *(unsigned*)&pk;
        }
        af[mf][ks] = *(bf16x8*)w;
      }
    #pragma unroll
    for (int ks = 0; ks < 2; ++ks)
      #pragma unroll
      for (int nf = 0; nf < 8; ++nf) {
        bf16x8 bfr = *(const bf16x8*)&St[(nf * 16 + mrow) * RS2 + ks * 16 + q * 4];
        acc[0][nf] = __builtin_amdgcn_mfma_f32_16x16x32_bf16(af[0][ks], bfr, acc[0][nf], 0, 0, 0);
        acc[1][nf] = __builtin_amdgcn_mfma_f32_16x16x32_bf16(af[1][ks], bfr, acc[1][nf], 0, 0, 0);
      }
    __syncthreads();
  }

  #pragma unroll
  for (int mf = 0; mf < 2; ++mf) {
    int pb = p0 + wave * 32 + mf * 16 + q * 4;
    #pragma unroll
    for (int nf = 0; nf < 8; ++nf) {
      int g = nf * 16 + mrow;
      float* op = out + ((size_t)b * LL + pb) * GG + g;
      #pragma unroll
      for (int r = 0; r < 4; ++r) op[(size_t)r * GG] = acc[mf][nf][r];
    }
  }
}

extern "C" void kernel_launch(void* const* d_in, const int* in_sizes, int n_in,
                              void* d_out, int out_size, void* d_ws, size_t ws_size,
                              hipStream_t stream) {
  const int*   idx    = (const int*)d_in[0];
  const float* x      = (const float*)d_in[5];
  const float* emb1   = (const float*)d_in[6];
  const float* emb2   = (const float*)d_in[7];
  const float* lin1_w = (const float*)d_in[8];
  const float* lin1_b = (const float*)d_in[9];
  const float* lin2_w = (const float*)d_in[10];
  const float* lin2_b = (const float*)d_in[11];
  const float* mlp_w  = (const float*)d_in[12];
  const float* mlp_b  = (const float*)d_in[13];
  const float* W_sel  = (const float*)d_in[14];  // [8,128,1]; only h=0 row used
  float* out = (float*)d_out;

  float* ws = (float*)d_ws;
  float* n1  = ws;                                          // 32768 floats
  float* n2  = ws + 32768;
  float* n1T = ws + 65536;
  float* n2T = ws + 98304;
  __hip_bfloat16* adjT16  = (__hip_bfloat16*)(ws + 131072); // 512*512 bf16
  __hip_bfloat16* RT      = (__hip_bfloat16*)(ws + 262144); // 32*128*512 bf16
  __hip_bfloat16* seriesT = (__hip_bfloat16*)(ws + 1310720);

  ga_nodes<<<NN, 64, 0, stream>>>(idx, emb1, emb2, lin1_w, lin1_b,
                                  lin2_w, lin2_b, n1, n2, n1T, n2T);
  ga_adjT<<<dim3(NN / 64, NN / 16), 256, 0, stream>>>(n1, n2, n1T, n2T, adjT16);
  ga_mlp<<<dim3(16, BB), 256, 0, stream>>>(x, mlp_w, mlp_b, W_sel, RT);
  ga_scores_mfma<<<dim3(8, BB), 256, 0, stream>>>(adjT16, RT, seriesT);
  ga_V_mfma<<<dim3(LL / 128, BB), 256, 0, stream>>>(x, seriesT, out);
}